// Round 5
// baseline (145.740 us; speedup 1.0000x reference)
//
#include <hip/hip_runtime.h>
#include <math.h>

typedef unsigned int uint32;
typedef unsigned short u16;

typedef __bf16 bf16x8 __attribute__((ext_vector_type(8)));
typedef float f32x4 __attribute__((ext_vector_type(4)));

constexpr int NB = 8, NC = 256, NN = 4096;

// Static device scratch (avoids any dependence on ws_size). All fully
// rewritten every launch; no state carried between calls.
__device__ __attribute__((aligned(16))) u16   g_x2h[NB * NN * NC];  // 16 MB
__device__ __attribute__((aligned(16))) u16   g_x2l[NB * NN * NC];  // 16 MB
__device__ __attribute__((aligned(16))) u16   g_wgh[NC * NC];
__device__ __attribute__((aligned(16))) u16   g_wgl[NC * NC];
__device__ __attribute__((aligned(16))) float g_acc[NB * NN * NC];  // 33.5 MB (dinv[n]*h)

__device__ __forceinline__ u16 bf16_rne(float f) {
    uint32 u = __float_as_uint(f);
    u += 0x7FFFu + ((u >> 16) & 1u);
    return (u16)(u >> 16);
}

__device__ __forceinline__ float dinv_of(int n) {
    int lo = n - 9; lo = lo < 0 ? 0 : lo;
    int hi = n + 9; hi = hi > NN - 1 ? NN - 1 : hi;
    return 1.0f / sqrtf((float)(hi - lo + 1));  // deg incl. self-loop
}

// ---------------------------------------------------------------------------
// K0: (a) permute x -> x2[b][n][k] with n = ch + 256*t, x2[n][k] = x[b][ch][16k+t],
//     split fp32 into bf16 hi/lo.  (b) transpose+split Wg -> Wgt[c][k] hi/lo.
// ---------------------------------------------------------------------------
__global__ __launch_bounds__(256) void kprep(const float* __restrict__ x,
                                             const float* __restrict__ wg) {
    __shared__ float sm[4096];
    const int bid = blockIdx.x, tid = threadIdx.x;
    if (bid < NB * NC) {
        const int b = bid >> 8, ch = bid & 255;
        // load one 16KB channel plane, coalesced
        const float4* src = reinterpret_cast<const float4*>(x) + ((size_t)(b * NC + ch) << 10);
        float4* s4 = reinterpret_cast<float4*>(sm);
#pragma unroll
        for (int v = 0; v < 4; ++v) s4[v * 256 + tid] = src[v * 256 + tid];
        __syncthreads();
        const int t = tid & 15, kb = tid >> 4;  // row t of 16, k-block of 16
        uint32 hp[8], lp[8];
#pragma unroll
        for (int w = 0; w < 8; ++w) {
            float f0 = sm[256 * kb + 16 * (2 * w) + t];      // s = 16k + t
            float f1 = sm[256 * kb + 16 * (2 * w + 1) + t];
            u16 h0 = bf16_rne(f0), h1 = bf16_rne(f1);
            float r0 = f0 - __uint_as_float((uint32)h0 << 16);
            float r1 = f1 - __uint_as_float((uint32)h1 << 16);
            hp[w] = (uint32)h0 | ((uint32)h1 << 16);
            lp[w] = (uint32)bf16_rne(r0) | ((uint32)bf16_rne(r1) << 16);
        }
        const int n = ch + (t << 8);
        const size_t off = (((size_t)b << 12) + n) * NC + kb * 16;
        uint4* dh = reinterpret_cast<uint4*>(g_x2h + off);
        uint4* dl = reinterpret_cast<uint4*>(g_x2l + off);
        dh[0] = make_uint4(hp[0], hp[1], hp[2], hp[3]);
        dh[1] = make_uint4(hp[4], hp[5], hp[6], hp[7]);
        dl[0] = make_uint4(lp[0], lp[1], lp[2], lp[3]);
        dl[1] = make_uint4(lp[4], lp[5], lp[6], lp[7]);
    } else {
        // Wg transpose+split: 64 blocks, each one 32x32 tile
        const int b2 = bid - NB * NC;
        const int k0 = (b2 >> 3) * 32, c0 = (b2 & 7) * 32;
        {
            const int r = tid >> 3, cq = tid & 7;
            float4 v = *reinterpret_cast<const float4*>(wg + (k0 + r) * NC + c0 + cq * 4);
            float* d = sm + r * 33 + cq * 4;
            d[0] = v.x; d[1] = v.y; d[2] = v.z; d[3] = v.w;
        }
        __syncthreads();
        const int c = tid >> 3, kq = tid & 7;
        uint32 hp[2], lp[2];
#pragma unroll
        for (int w = 0; w < 2; ++w) {
            float f0 = sm[(kq * 4 + 2 * w) * 33 + c];
            float f1 = sm[(kq * 4 + 2 * w + 1) * 33 + c];
            u16 h0 = bf16_rne(f0), h1 = bf16_rne(f1);
            float r0 = f0 - __uint_as_float((uint32)h0 << 16);
            float r1 = f1 - __uint_as_float((uint32)h1 << 16);
            hp[w] = (uint32)h0 | ((uint32)h1 << 16);
            lp[w] = (uint32)bf16_rne(r0) | ((uint32)bf16_rne(r1) << 16);
        }
        const int off = (c0 + c) * NC + k0 + kq * 4;
        *reinterpret_cast<uint2*>(g_wgh + off) = make_uint2(hp[0], hp[1]);
        *reinterpret_cast<uint2*>(g_wgl + off) = make_uint2(lp[0], lp[1]);
    }
}

// ---------------------------------------------------------------------------
// A: g[b][n][c] = dinv[n] * (x2[n,:] @ Wg)[c]  via split-bf16 MFMA (3 products).
// 256 blocks (8 batch x 32 row-tiles), 8 waves (2M x 4N), wave = 64x64 tile.
// Register-direct fragment loads (no LDS) from L2-resident pre-split buffers.
// ---------------------------------------------------------------------------
__device__ __forceinline__ bf16x8 ldb8(const u16* p) {
    return __builtin_bit_cast(bf16x8, *reinterpret_cast<const uint4*>(p));
}

__global__ __launch_bounds__(512, 2) void kgemm() {
    const int bid = blockIdx.x, tid = threadIdx.x;
    const int b = bid >> 5, rblk = bid & 31;
    const int w = tid >> 6, l = tid & 63;
    const int wm = w >> 2, wn = w & 3;
    const int r0 = rblk * 128 + wm * 64;
    const int c0 = wn * 64;
    const int lr = l & 15, lk = l >> 4;

    const u16* xh = g_x2h + (((size_t)b << 12) + r0 + lr) * NC + lk * 8;
    const u16* xl = g_x2l + (((size_t)b << 12) + r0 + lr) * NC + lk * 8;
    const u16* wh = g_wgh + (size_t)(c0 + lr) * NC + lk * 8;
    const u16* wl = g_wgl + (size_t)(c0 + lr) * NC + lk * 8;

    f32x4 acc[4][4] = {};

    for (int kb = 0; kb < NC; kb += 32) {
        bf16x8 ah[4], al[4], bh[4], bl[4];
#pragma unroll
        for (int i = 0; i < 4; ++i) {
            ah[i] = ldb8(xh + kb + i * 16 * NC);
            al[i] = ldb8(xl + kb + i * 16 * NC);
            bh[i] = ldb8(wh + kb + i * 16 * NC);
            bl[i] = ldb8(wl + kb + i * 16 * NC);
        }
#pragma unroll
        for (int i = 0; i < 4; ++i)
#pragma unroll
            for (int j = 0; j < 4; ++j) {
                acc[i][j] = __builtin_amdgcn_mfma_f32_16x16x32_bf16(ah[i], bh[j], acc[i][j], 0, 0, 0);
                acc[i][j] = __builtin_amdgcn_mfma_f32_16x16x32_bf16(ah[i], bl[j], acc[i][j], 0, 0, 0);
                acc[i][j] = __builtin_amdgcn_mfma_f32_16x16x32_bf16(al[i], bh[j], acc[i][j], 0, 0, 0);
            }
    }

    // D layout: col = lane&15, row = (lane>>4)*4 + v  [m89-verified]
#pragma unroll
    for (int i = 0; i < 4; ++i) {
#pragma unroll
        for (int v = 0; v < 4; ++v) {
            const int n = r0 + 16 * i + 4 * lk + v;
            const float di = dinv_of(n);
            float* gp = g_acc + (((size_t)b << 12) + n) * NC + c0 + lr;
#pragma unroll
            for (int j = 0; j < 4; ++j) gp[16 * j] = acc[i][j][v] * di;
        }
    }
}

// ---------------------------------------------------------------------------
// B: out[b][c][n] = dinv[n] * sum_{|j-n|<=9} g[b][j][c] + bias[c]
// tile 64n x 64c; halo-staged LDS; per-thread sliding window (lane along c);
// LDS round-trip for coalesced transposed stores.
// ---------------------------------------------------------------------------
__global__ __launch_bounds__(256) void kband(const float* __restrict__ bias,
                                             float* __restrict__ out) {
    __shared__ float sm[5248];  // 82 rows x 64 cols
    const int bid = blockIdx.x, tid = threadIdx.x;
    const int b = bid >> 8;
    const int nt = (bid >> 2) & 63;
    const int ct = bid & 3;
    const int n0 = nt * 64, c0 = ct * 64;

    const float* gsrc = g_acc + (((size_t)b << 12)) * NC;
    for (int it = 0; it < 6; ++it) {
        int idx = it * 256 + tid;
        if (idx < 82 * 16) {
            int jj = idx >> 4, c4 = idx & 15;
            int j = n0 - 9 + jj;
            float4 v = make_float4(0.f, 0.f, 0.f, 0.f);
            if (j >= 0 && j < NN)
                v = *reinterpret_cast<const float4*>(gsrc + (size_t)j * NC + c0 + c4 * 4);
            *reinterpret_cast<float4*>(sm + jj * 64 + c4 * 4) = v;
        }
    }
    __syncthreads();

    const int c = tid & 63, ng = tid >> 6;
    const int nl = ng * 16;
    float sum = 0.f;
#pragma unroll
    for (int q = 0; q < 19; ++q) sum += sm[(nl + q) * 64 + c];
    float ov[16];
    ov[0] = sum;
#pragma unroll
    for (int q = 1; q < 16; ++q) {
        sum += sm[(nl + 18 + q) * 64 + c] - sm[(nl + q - 1) * 64 + c];
        ov[q] = sum;
    }
    const float bc = bias[c0 + c];
#pragma unroll
    for (int q = 0; q < 16; ++q) ov[q] = ov[q] * dinv_of(n0 + nl + q) + bc;

    __syncthreads();
#pragma unroll
    for (int q = 0; q < 16; ++q) sm[c * 68 + nl + q] = ov[q];
    __syncthreads();

#pragma unroll
    for (int it = 0; it < 4; ++it) {
        int idx = it * 256 + tid;
        int cr = idx >> 4, n4 = idx & 15;
        float4 v = *reinterpret_cast<const float4*>(sm + cr * 68 + n4 * 4);
        *reinterpret_cast<float4*>(out + ((size_t)(b * NC + c0 + cr) << 12) + n0 + n4 * 4) = v;
    }
}

extern "C" void kernel_launch(void* const* d_in, const int* in_sizes, int n_in,
                              void* d_out, int out_size, void* d_ws, size_t ws_size,
                              hipStream_t stream) {
    const float* x  = (const float*)d_in[0];
    const float* wg = (const float*)d_in[1];
    const float* bs = (const float*)d_in[2];
    float* out = (float*)d_out;

    hipLaunchKernelGGL(kprep, dim3(NB * NC + 64), dim3(256), 0, stream, x, wg);
    hipLaunchKernelGGL(kgemm, dim3(NB * 32), dim3(512), 0, stream);
    hipLaunchKernelGGL(kband, dim3(NB * 256), dim3(256), 0, stream, bs, out);
}